// Round 19
// baseline (137.841 us; speedup 1.0000x reference)
//
#include <hip/hip_runtime.h>
#include <math.h>

#define T_N 100000
#define H_N 256
#define NT16 (T_N / 16)        // 6250 16-row tiles, exact
#define NB_AT 256              // k_at grid
#define WPB 12                 // waves per block
#define NTHR (WPB * 64)        // 768 threads

typedef __attribute__((ext_vector_type(8))) __bf16 bf16x8;
typedef __attribute__((ext_vector_type(4))) float f32x4;

// ws layout (bytes):
//       0 : WmT bf16 [256][256]   (131072)
//  131072 : proj f32 [256]        (1024)
//  132096 : At   f32 [100000]     (400000)
//  532096 : part2 float2[256]     (2048)
//  536192 : s1g  f32[256]         (1024)
//  537216 : s0g  f32[256]         (1024)
//  538240 : lse  f32              (4)
//  538244 : cnt  int              (4)

__device__ __forceinline__ float tanh_fast(float x) {
    float e = __expf(2.0f * x);
    return 1.0f - 2.0f / (e + 1.0f);
}

// ---------------------------------------------------------------- prep
__global__ __launch_bounds__(256) void k_prep(const float* __restrict__ Wm,
                                              const float* __restrict__ hc,
                                              const float* __restrict__ W1,
                                              __bf16* __restrict__ WmT,
                                              float* __restrict__ proj,
                                              float* __restrict__ s1g,
                                              float* __restrict__ s0g,
                                              int* __restrict__ cnt) {
    const int j = blockIdx.x;
    const int t = threadIdx.x;
    WmT[j * H_N + t] = (__bf16)Wm[t * H_N + j];   // B^T, k-contiguous
    __shared__ float red[H_N];
    red[t] = hc[t] * W1[j * H_N + t];
    __syncthreads();
    for (int off = 128; off > 0; off >>= 1) {
        if (t < off) red[t] += red[t + off];
        __syncthreads();
    }
    if (t == 0) proj[j] = red[0];
    if (j == 0) { s1g[t] = 0.0f; s0g[t] = 0.0f; }
    if (j == 0 && t == 0) *cnt = 0;
}

// ---------------------------------------------------------------- fused At + LSE + ct partials
// 768 thr = 12 INDEPENDENT waves, no main-loop barriers. Tiles distributed by
// a global atomic counter (perfect balance, ~2 grabs/wave). Per iteration:
// af(t) loads -> ct-FMA for PREVIOUS tile (consumes loop-carried x,pprev) ->
// x(t) loads (L1-hot, same tile as af; loop-carried so the allocator CANNOT
// sink them - R14-proven) -> jb MFMA (dual chains) -> butterfly -> At/LSE.
__global__ __launch_bounds__(NTHR, 3) void k_at(const float* __restrict__ Mt,
                                                const __bf16* __restrict__ WmT,
                                                const float* __restrict__ proj,
                                                const float* __restrict__ V,
                                                float* __restrict__ At,
                                                float2* __restrict__ part2,
                                                float* __restrict__ s1g,
                                                float* __restrict__ s0g,
                                                int* __restrict__ cnt) {
    const int tid = threadIdx.x;
    const int lane = tid & 63;
    const int w = tid >> 6;     // 0..11
    const int l15 = lane & 15;
    const int lg = lane >> 4;   // 0..3

    struct SMem {
        __align__(16) char sB[131072];   // [n=256][k=256] bf16, XOR-swizzled
        float pj[256];
        float vj[256];
        float lsem[WPB], lses[WPB];
    };
    __shared__ SMem sm;

    // ---- B prologue (WmT L2-hot after k_prep)
    for (int g = tid; g < 8192; g += NTHR) {
        const int n = g >> 5;
        const int c = g & 31;
        const bf16x8 v = *(const bf16x8*)(WmT + n * H_N + c * 8);
        *(bf16x8*)(&sm.sB[(n * 512 + c * 16) ^ ((n & 7) << 4)]) = v;
    }
    if (tid < 256) { sm.pj[tid] = proj[tid]; sm.vj[tid] = V[tid]; }
    __syncthreads();   // ONLY barrier before the epilogue

    float lm = -1e30f, ls = 0.0f;
    float s1a[4] = {0.f, 0.f, 0.f, 0.f};
    float s0a[4] = {0.f, 0.f, 0.f, 0.f};

    // wave-level tile grab
    auto grab = [&]() -> int {
        int t;
        if (lane == 0) t = atomicAdd(cnt, 1);
        return __shfl(t, 0);
    };

    float4 x[16];      // loop-carried ct operands (cannot be sunk)
    float pprev[4];    // loop-carried row sums of the previous tile
    int have_prev = 0;

    int t = grab();
    while (t < NT16) {
        const float* arow = Mt + (size_t)(t * 16 + l15) * H_N;
        const float* crow = Mt + (size_t)t * 16 * H_N + lane * 4;

        // ---- A fragments (cvt at load; 32 VGPR)
        bf16x8 af[8];
#pragma unroll
        for (int ks = 0; ks < 8; ++ks) {
            const float4 a0 = *(const float4*)(arow + 32 * ks + 8 * lg);
            const float4 a1 = *(const float4*)(arow + 32 * ks + 8 * lg + 4);
            af[ks][0] = (__bf16)a0.x; af[ks][1] = (__bf16)a0.y;
            af[ks][2] = (__bf16)a0.z; af[ks][3] = (__bf16)a0.w;
            af[ks][4] = (__bf16)a1.x; af[ks][5] = (__bf16)a1.y;
            af[ks][6] = (__bf16)a1.z; af[ks][7] = (__bf16)a1.w;
        }

        // ---- ct-FMA for the PREVIOUS tile (frees x before the overwrite)
        if (have_prev) {
#pragma unroll
            for (int r = 0; r < 16; ++r) {
                const float atr = __shfl(pprev[r & 3], 16 * (r >> 2));
                s1a[0] += atr * x[r].x; s1a[1] += atr * x[r].y;
                s1a[2] += atr * x[r].z; s1a[3] += atr * x[r].w;
                s0a[0] += x[r].x; s0a[1] += x[r].y;
                s0a[2] += x[r].z; s0a[3] += x[r].w;
            }
        }

        // ---- ct loads for THIS tile (L1/L2-hot: af just fetched these rows);
        //      consumed next iteration -> loop-carried, allocator must keep them
#pragma unroll
        for (int r = 0; r < 16; ++r)
            x[r] = *(const float4*)(crow + (size_t)r * H_N);

        // ---- jb loop: 16 col-blocks, dual chains, 2 blocks in flight
        float pacc[4] = {0.f, 0.f, 0.f, 0.f};
#pragma unroll 2
        for (int jb = 0; jb < 16; ++jb) {
            f32x4 accA = {0.f, 0.f, 0.f, 0.f};
            f32x4 accB = {0.f, 0.f, 0.f, 0.f};
            const int n = 16 * jb + l15;
            const int nb = n * 512;
            const int nswz = (n & 7) << 4;
#pragma unroll
            for (int ks = 0; ks < 4; ++ks) {
                const bf16x8 bfA = *(const bf16x8*)(
                    &sm.sB[nb + (((32 * ks + 8 * lg) * 2) ^ nswz)]);
                const bf16x8 bfB = *(const bf16x8*)(
                    &sm.sB[nb + (((32 * (ks + 4) + 8 * lg) * 2) ^ nswz)]);
                accA = __builtin_amdgcn_mfma_f32_16x16x32_bf16(af[ks], bfA, accA, 0, 0, 0);
                accB = __builtin_amdgcn_mfma_f32_16x16x32_bf16(af[ks + 4], bfB, accB, 0, 0, 0);
            }
            const float pjv = sm.pj[n], vjv = sm.vj[n];
#pragma unroll
            for (int i = 0; i < 4; ++i)
                pacc[i] += tanh_fast(accA[i] + accB[i] + pjv) * vjv;
        }

        // ---- row sums: butterfly over the 16 lanes of each lg group
#pragma unroll
        for (int i = 0; i < 4; ++i) {
            float q = pacc[i];
            q += __shfl_xor(q, 1);
            q += __shfl_xor(q, 2);
            q += __shfl_xor(q, 4);
            q += __shfl_xor(q, 8);
            pprev[i] = q;
        }
        if (l15 == 0) {
#pragma unroll
            for (int i = 0; i < 4; ++i) {
                const float at = pprev[i];
                At[t * 16 + 4 * lg + i] = at;
                if (at > lm) { ls = ls * __expf(lm - at) + 1.0f; lm = at; }
                else ls += __expf(at - lm);
            }
        }
        have_prev = 1;
        t = grab();
    }

    // ---- drain: ct-FMA for the final tile
    if (have_prev) {
#pragma unroll
        for (int r = 0; r < 16; ++r) {
            const float atr = __shfl(pprev[r & 3], 16 * (r >> 2));
            s1a[0] += atr * x[r].x; s1a[1] += atr * x[r].y;
            s1a[2] += atr * x[r].z; s1a[3] += atr * x[r].w;
            s0a[0] += x[r].x; s0a[1] += x[r].y;
            s0a[2] += x[r].z; s0a[3] += x[r].w;
        }
    }

    // ---- wave LSE partial -> shared
#pragma unroll
    for (int d = 1; d < 64; d <<= 1) {
        const float m2 = __shfl_xor(lm, d), s2 = __shfl_xor(ls, d);
        const float M = fmaxf(lm, m2);
        ls = ls * __expf(lm - M) + s2 * __expf(m2 - M);
        lm = M;
    }
    if (lane == 0) { sm.lsem[w] = lm; sm.lses[w] = ls; }

    // ---- block reduce of ct partials (reuse sB region)
    __syncthreads();
    float* red1 = (float*)&sm.sB[0];       // [12][256]
    float* red2 = (float*)&sm.sB[65536];   // [12][256]
#pragma unroll
    for (int q = 0; q < 4; ++q) {
        red1[w * 256 + lane * 4 + q] = s1a[q];
        red2[w * 256 + lane * 4 + q] = s0a[q];
    }
    __syncthreads();
    if (tid < 256) {
        float a = 0.f;
#pragma unroll
        for (int g = 0; g < WPB; ++g) a += red1[g * 256 + tid];
        atomicAdd(&s1g[tid], a);
    } else if (tid < 512) {
        const int c = tid - 256;
        float a = 0.f;
#pragma unroll
        for (int g = 0; g < WPB; ++g) a += red2[g * 256 + c];
        atomicAdd(&s0g[c], a);
    } else if (tid == 512) {
        float m = sm.lsem[0], s = sm.lses[0];
#pragma unroll
        for (int g = 1; g < WPB; ++g) {
            const float m2 = sm.lsem[g], s2 = sm.lses[g];
            const float M = fmaxf(m, m2);
            s = s * __expf(m - M) + s2 * __expf(m2 - M);
            m = M;
        }
        part2[blockIdx.x] = make_float2(m, s);
    }
}

// ---------------------------------------------------------------- final: LSE + ct
__global__ __launch_bounds__(256) void k_final(const float2* __restrict__ part2,
                                               const float* __restrict__ s1g,
                                               const float* __restrict__ s0g,
                                               float* __restrict__ lse,
                                               float* __restrict__ out) {
    const int tid = threadIdx.x;
    __shared__ float ms[256], ss[256];
    const float2 p = part2[tid];
    ms[tid] = p.x; ss[tid] = p.y;
    __syncthreads();
    for (int off = 128; off > 0; off >>= 1) {
        if (tid < off) {
            const float m2 = ms[tid + off], s2 = ss[tid + off];
            const float M = fmaxf(ms[tid], m2);
            ss[tid] = ss[tid] * __expf(ms[tid] - M) + s2 * __expf(m2 - M);
            ms[tid] = M;
        }
        __syncthreads();
    }
    __shared__ float Ls;
    if (tid == 0) { Ls = ms[0] + logf(ss[0]); *lse = Ls; }
    __syncthreads();
    out[T_N + tid] = s1g[tid] - Ls * s0g[tid];
}

// ---------------------------------------------------------------- alphat = At - LSE
__global__ __launch_bounds__(256) void k_alpha(const float* __restrict__ At,
                                               const float* __restrict__ lse,
                                               float* __restrict__ out) {
    const float L = *lse;
    const int i4 = blockIdx.x * 256 + threadIdx.x;
    if (i4 < T_N / 4) {
        float4 a = *(const float4*)(At + i4 * 4);
        a.x -= L; a.y -= L; a.z -= L; a.w -= L;
        *(float4*)(out + i4 * 4) = a;
    }
}

// ----------------------------------------------------------------
extern "C" void kernel_launch(void* const* d_in, const int* in_sizes, int n_in,
                              void* d_out, int out_size, void* d_ws, size_t ws_size,
                              hipStream_t stream) {
    const float* inputs = (const float*)d_in[0];  // (T, H)
    const float* hc     = (const float*)d_in[1];  // (1, H)
    const float* Wm     = (const float*)d_in[2];  // (H, H)
    const float* V      = (const float*)d_in[3];  // (H, 1)
    const float* W1     = (const float*)d_in[4];  // (H, H)
    float* out = (float*)d_out;                   // [alphat (T) | ct (H)]

    char* ws = (char*)d_ws;
    __bf16* WmT  = (__bf16*)ws;
    float* proj  = (float*)(ws + 131072);
    float* At    = (float*)(ws + 132096);
    float2* p2   = (float2*)(ws + 532096);
    float* s1g   = (float*)(ws + 536192);
    float* s0g   = (float*)(ws + 537216);
    float* lse   = (float*)(ws + 538240);
    int* cnt     = (int*)(ws + 538244);

    k_prep<<<256, 256, 0, stream>>>(Wm, hc, W1, WmT, proj, s1g, s0g, cnt);
    k_at<<<NB_AT, NTHR, 0, stream>>>(inputs, WmT, proj, V, At, p2, s1g, s0g, cnt);
    k_final<<<1, 256, 0, stream>>>(p2, s1g, s0g, lse, out);
    k_alpha<<<98, 256, 0, stream>>>(At, lse, out);
}

// Round 20
// 99.093 us; speedup vs baseline: 1.3910x; 1.3910x over previous
//
#include <hip/hip_runtime.h>
#include <math.h>

#define T_N 100000
#define H_N 256
#define NT32 (T_N / 32)        // 3125 32-row tiles, exact
#define NB_AT 256              // k_at grid
#define WPB 13                 // waves per block
#define NTHR (WPB * 64)        // 832 threads

typedef __attribute__((ext_vector_type(8))) __bf16 bf16x8;
typedef __attribute__((ext_vector_type(4))) float f32x4;

// ws layout (bytes):
//       0 : WmT bf16 [256][256]   (131072)
//  131072 : proj f32 [256]        (1024)
//  132096 : At   f32 [100000]     (400000)
//  532096 : part2 float2[256]     (2048)
//  536192 : s1g  f32[256]         (1024)
//  537216 : s0g  f32[256]         (1024)
//  538240 : lse  f32              (4)

__device__ __forceinline__ float tanh_fast(float x) {
    float e = __expf(2.0f * x);
    return 1.0f - 2.0f / (e + 1.0f);
}

// ---------------------------------------------------------------- prep
__global__ __launch_bounds__(256) void k_prep(const float* __restrict__ Wm,
                                              const float* __restrict__ hc,
                                              const float* __restrict__ W1,
                                              __bf16* __restrict__ WmT,
                                              float* __restrict__ proj,
                                              float* __restrict__ s1g,
                                              float* __restrict__ s0g) {
    const int j = blockIdx.x;
    const int t = threadIdx.x;
    WmT[j * H_N + t] = (__bf16)Wm[t * H_N + j];   // B^T, k-contiguous
    __shared__ float red[H_N];
    red[t] = hc[t] * W1[j * H_N + t];
    __syncthreads();
    for (int off = 128; off > 0; off >>= 1) {
        if (t < off) red[t] += red[t + off];
        __syncthreads();
    }
    if (t == 0) proj[j] = red[0];
    if (j == 0) { s1g[t] = 0.0f; s0g[t] = 0.0f; }
}

// ---------------------------------------------------------------- fused At + LSE + ct partials
// R15 base: 832 thr = 13 waves, ONE 32-row tile per wave, no main-loop
// barriers, B in LDS. NEW: ct partials computed IN-REGISTER from the af
// fragments already loaded (no fp32 re-read of Mt): per (ks,j) slot,
// cs1 = at0*a0 + at1*a1 is butterfly-summed over the 16-lane row group;
// owner lane (l15 == 2ks+(j>>2)) accumulates. Removes ~49 MB of L2-missed
// HBM traffic and the 16-load latency exposure; adds ~1.1K VALU instr/tile.
__global__ __launch_bounds__(NTHR, 4) void k_at(const float* __restrict__ Mt,
                                                const __bf16* __restrict__ WmT,
                                                const float* __restrict__ proj,
                                                const float* __restrict__ V,
                                                float* __restrict__ At,
                                                float2* __restrict__ part2,
                                                float* __restrict__ s1g,
                                                float* __restrict__ s0g) {
    const int tid = threadIdx.x;
    const int lane = tid & 63;
    const int w = tid >> 6;     // 0..12
    const int l15 = lane & 15;
    const int lg = lane >> 4;   // 0..3

    struct SMem {
        __align__(16) char sB[131072];   // [n=256][k=256] bf16, XOR-swizzled
        float pj[256];
        float vj[256];
        float lsem[WPB], lses[WPB];
    };
    __shared__ SMem sm;

    // ---- B prologue (WmT L2-hot after k_prep)
    for (int g = tid; g < 8192; g += NTHR) {
        const int n = g >> 5;
        const int c = g & 31;
        const bf16x8 v = *(const bf16x8*)(WmT + n * H_N + c * 8);
        *(bf16x8*)(&sm.sB[(n * 512 + c * 16) ^ ((n & 7) << 4)]) = v;
    }
    if (tid < 256) { sm.pj[tid] = proj[tid]; sm.vj[tid] = V[tid]; }
    __syncthreads();

    const int gw = blockIdx.x * WPB + w;   // global wave id = tile id
    float lm = -1e30f, ls = 0.0f;
    float s1a[4] = {0.f, 0.f, 0.f, 0.f};
    float s0a[4] = {0.f, 0.f, 0.f, 0.f};

    if (gw < NT32) {
        const int t0 = gw * 32;
        const float* arow0 = Mt + (size_t)(t0 + l15) * H_N;
        const float* arow1 = Mt + (size_t)(t0 + 16 + l15) * H_N;

        // ---- A fragments for both row-groups (cvt at load; 64 VGPR total)
        bf16x8 af0[8], af1[8];
#pragma unroll
        for (int ks = 0; ks < 8; ++ks) {
            const float4 a0 = *(const float4*)(arow0 + 32 * ks + 8 * lg);
            const float4 a1 = *(const float4*)(arow0 + 32 * ks + 8 * lg + 4);
            af0[ks][0] = (__bf16)a0.x; af0[ks][1] = (__bf16)a0.y;
            af0[ks][2] = (__bf16)a0.z; af0[ks][3] = (__bf16)a0.w;
            af0[ks][4] = (__bf16)a1.x; af0[ks][5] = (__bf16)a1.y;
            af0[ks][6] = (__bf16)a1.z; af0[ks][7] = (__bf16)a1.w;
            const float4 b0 = *(const float4*)(arow1 + 32 * ks + 8 * lg);
            const float4 b1 = *(const float4*)(arow1 + 32 * ks + 8 * lg + 4);
            af1[ks][0] = (__bf16)b0.x; af1[ks][1] = (__bf16)b0.y;
            af1[ks][2] = (__bf16)b0.z; af1[ks][3] = (__bf16)b0.w;
            af1[ks][4] = (__bf16)b1.x; af1[ks][5] = (__bf16)b1.y;
            af1[ks][6] = (__bf16)b1.z; af1[ks][7] = (__bf16)b1.w;
        }

        // ---- jb loop: 16 col-blocks; B-reads shared by both row-groups
        float pacc0[4] = {0.f, 0.f, 0.f, 0.f};
        float pacc1[4] = {0.f, 0.f, 0.f, 0.f};
#pragma unroll 1
        for (int jb = 0; jb < 16; ++jb) {
            f32x4 a0A = {0.f, 0.f, 0.f, 0.f}, a0B = {0.f, 0.f, 0.f, 0.f};
            f32x4 a1A = {0.f, 0.f, 0.f, 0.f}, a1B = {0.f, 0.f, 0.f, 0.f};
            const int n = 16 * jb + l15;
            const int nb = n * 512;
            const int nswz = (n & 7) << 4;
#pragma unroll
            for (int ks = 0; ks < 4; ++ks) {
                const bf16x8 bfA = *(const bf16x8*)(
                    &sm.sB[nb + (((32 * ks + 8 * lg) * 2) ^ nswz)]);
                const bf16x8 bfB = *(const bf16x8*)(
                    &sm.sB[nb + (((32 * (ks + 4) + 8 * lg) * 2) ^ nswz)]);
                a0A = __builtin_amdgcn_mfma_f32_16x16x32_bf16(af0[ks], bfA, a0A, 0, 0, 0);
                a1A = __builtin_amdgcn_mfma_f32_16x16x32_bf16(af1[ks], bfA, a1A, 0, 0, 0);
                a0B = __builtin_amdgcn_mfma_f32_16x16x32_bf16(af0[ks + 4], bfB, a0B, 0, 0, 0);
                a1B = __builtin_amdgcn_mfma_f32_16x16x32_bf16(af1[ks + 4], bfB, a1B, 0, 0, 0);
            }
            const float pjv = sm.pj[n], vjv = sm.vj[n];
#pragma unroll
            for (int i = 0; i < 4; ++i) {
                pacc0[i] += tanh_fast(a0A[i] + a0B[i] + pjv) * vjv;
                pacc1[i] += tanh_fast(a1A[i] + a1B[i] + pjv) * vjv;
            }
        }

        // ---- row sums: butterfly over the 16 lanes of each lg group
        float p0[4], p1[4];
#pragma unroll
        for (int i = 0; i < 4; ++i) {
            float q0 = pacc0[i], q1 = pacc1[i];
            q0 += __shfl_xor(q0, 1); q1 += __shfl_xor(q1, 1);
            q0 += __shfl_xor(q0, 2); q1 += __shfl_xor(q1, 2);
            q0 += __shfl_xor(q0, 4); q1 += __shfl_xor(q1, 4);
            q0 += __shfl_xor(q0, 8); q1 += __shfl_xor(q1, 8);
            p0[i] = q0; p1[i] = q1;
        }
        if (l15 == 0) {
#pragma unroll
            for (int i = 0; i < 4; ++i) {
                const float a0v = p0[i], a1v = p1[i];
                At[t0 + 4 * lg + i] = a0v;
                At[t0 + 16 + 4 * lg + i] = a1v;
                if (a0v > lm) { ls = ls * __expf(lm - a0v) + 1.0f; lm = a0v; }
                else ls += __expf(a0v - lm);
                if (a1v > lm) { ls = ls * __expf(lm - a1v) + 1.0f; lm = a1v; }
                else ls += __expf(a1v - lm);
            }
        }

        // ---- this lane's own-row At values (rows l15 and 16+l15)
        // row l15 = 4*(l15>>2) + (l15&3): value p?[l15&3] held by lanes of
        // group (l15>>2); all 16 lanes of a group hold identical p after the
        // butterfly, so shuffle each slot from lane 16*(l15>>2) and select.
        const int srcl = (l15 >> 2) * 16;
        const float q00 = __shfl(p0[0], srcl), q01 = __shfl(p0[1], srcl);
        const float q02 = __shfl(p0[2], srcl), q03 = __shfl(p0[3], srcl);
        const float q10 = __shfl(p1[0], srcl), q11 = __shfl(p1[1], srcl);
        const float q12 = __shfl(p1[2], srcl), q13 = __shfl(p1[3], srcl);
        const int i3 = l15 & 3;
        const float at0 = (i3 == 0) ? q00 : (i3 == 1) ? q01 : (i3 == 2) ? q02 : q03;
        const float at1 = (i3 == 0) ? q10 : (i3 == 1) ? q11 : (i3 == 2) ? q12 : q13;

        // ---- ct partials IN-REGISTER from af: per slot (ks,j), col
        // c = 32ks + 8lg + j; butterfly-sum over 16 row-lanes; owner
        // l15 == 2ks+(j>>2) keeps cols 32(l15>>1)+8lg+4(l15&1)+q.
#pragma unroll
        for (int ks = 0; ks < 8; ++ks) {
#pragma unroll
            for (int j = 0; j < 8; ++j) {
                const float a0 = (float)af0[ks][j];
                const float a1 = (float)af1[ks][j];
                float cs1 = at0 * a0 + at1 * a1;
                float cs0 = a0 + a1;
                cs1 += __shfl_xor(cs1, 1); cs0 += __shfl_xor(cs0, 1);
                cs1 += __shfl_xor(cs1, 2); cs0 += __shfl_xor(cs0, 2);
                cs1 += __shfl_xor(cs1, 4); cs0 += __shfl_xor(cs0, 4);
                cs1 += __shfl_xor(cs1, 8); cs0 += __shfl_xor(cs0, 8);
                if (l15 == 2 * ks + (j >> 2)) {
                    s1a[j & 3] += cs1;
                    s0a[j & 3] += cs0;
                }
            }
        }
    }

    // ---- wave LSE partial -> shared
#pragma unroll
    for (int d = 1; d < 64; d <<= 1) {
        const float m2 = __shfl_xor(lm, d), s2 = __shfl_xor(ls, d);
        const float M = fmaxf(lm, m2);
        ls = ls * __expf(lm - M) + s2 * __expf(m2 - M);
        lm = M;
    }
    if (lane == 0) { sm.lsem[w] = lm; sm.lses[w] = ls; }

    // ---- block reduce of ct partials (reuse sB region)
    __syncthreads();
    float* red1 = (float*)&sm.sB[0];       // [13][256]
    float* red2 = (float*)&sm.sB[65536];   // [13][256]
    {
        const int cbase = 32 * (l15 >> 1) + 8 * lg + 4 * (l15 & 1);
#pragma unroll
        for (int q = 0; q < 4; ++q) {
            red1[w * 256 + cbase + q] = s1a[q];
            red2[w * 256 + cbase + q] = s0a[q];
        }
    }
    __syncthreads();
    if (tid < 256) {
        float a = 0.f;
#pragma unroll
        for (int g = 0; g < WPB; ++g) a += red1[g * 256 + tid];
        atomicAdd(&s1g[tid], a);
    } else if (tid < 512) {
        const int c = tid - 256;
        float a = 0.f;
#pragma unroll
        for (int g = 0; g < WPB; ++g) a += red2[g * 256 + c];
        atomicAdd(&s0g[c], a);
    } else if (tid == 512) {
        float m = sm.lsem[0], s = sm.lses[0];
#pragma unroll
        for (int g = 1; g < WPB; ++g) {
            const float m2 = sm.lsem[g], s2 = sm.lses[g];
            const float M = fmaxf(m, m2);
            s = s * __expf(m - M) + s2 * __expf(m2 - M);
            m = M;
        }
        part2[blockIdx.x] = make_float2(m, s);
    }
}

// ---------------------------------------------------------------- final: LSE + ct
__global__ __launch_bounds__(256) void k_final(const float2* __restrict__ part2,
                                               const float* __restrict__ s1g,
                                               const float* __restrict__ s0g,
                                               float* __restrict__ lse,
                                               float* __restrict__ out) {
    const int tid = threadIdx.x;
    __shared__ float ms[256], ss[256];
    const float2 p = part2[tid];
    ms[tid] = p.x; ss[tid] = p.y;
    __syncthreads();
    for (int off = 128; off > 0; off >>= 1) {
        if (tid < off) {
            const float m2 = ms[tid + off], s2 = ss[tid + off];
            const float M = fmaxf(ms[tid], m2);
            ss[tid] = ss[tid] * __expf(ms[tid] - M) + s2 * __expf(m2 - M);
            ms[tid] = M;
        }
        __syncthreads();
    }
    __shared__ float Ls;
    if (tid == 0) { Ls = ms[0] + logf(ss[0]); *lse = Ls; }
    __syncthreads();
    out[T_N + tid] = s1g[tid] - Ls * s0g[tid];
}

// ---------------------------------------------------------------- alphat = At - LSE
__global__ __launch_bounds__(256) void k_alpha(const float* __restrict__ At,
                                               const float* __restrict__ lse,
                                               float* __restrict__ out) {
    const float L = *lse;
    const int i4 = blockIdx.x * 256 + threadIdx.x;
    if (i4 < T_N / 4) {
        float4 a = *(const float4*)(At + i4 * 4);
        a.x -= L; a.y -= L; a.z -= L; a.w -= L;
        *(float4*)(out + i4 * 4) = a;
    }
}

// ----------------------------------------------------------------
extern "C" void kernel_launch(void* const* d_in, const int* in_sizes, int n_in,
                              void* d_out, int out_size, void* d_ws, size_t ws_size,
                              hipStream_t stream) {
    const float* inputs = (const float*)d_in[0];  // (T, H)
    const float* hc     = (const float*)d_in[1];  // (1, H)
    const float* Wm     = (const float*)d_in[2];  // (H, H)
    const float* V      = (const float*)d_in[3];  // (H, 1)
    const float* W1     = (const float*)d_in[4];  // (H, H)
    float* out = (float*)d_out;                   // [alphat (T) | ct (H)]

    char* ws = (char*)d_ws;
    __bf16* WmT  = (__bf16*)ws;
    float* proj  = (float*)(ws + 131072);
    float* At    = (float*)(ws + 132096);
    float2* p2   = (float2*)(ws + 532096);
    float* s1g   = (float*)(ws + 536192);
    float* s0g   = (float*)(ws + 537216);
    float* lse   = (float*)(ws + 538240);

    k_prep<<<256, 256, 0, stream>>>(Wm, hc, W1, WmT, proj, s1g, s0g);
    k_at<<<NB_AT, NTHR, 0, stream>>>(inputs, WmT, proj, V, At, p2, s1g, s0g);
    k_final<<<1, 256, 0, stream>>>(p2, s1g, s0g, lse, out);
    k_alpha<<<98, 256, 0, stream>>>(At, lse, out);
}

// Round 21
// 86.291 us; speedup vs baseline: 1.5974x; 1.1484x over previous
//
#include <hip/hip_runtime.h>
#include <math.h>

#define T_N 100000
#define H_N 256
#define NT32 (T_N / 32)        // 3125 32-row tiles, exact
#define NB_AT 512              // k_at grid: 256 pairs x 2 halves, 2 blocks/CU
#define WPB 13                 // waves per block
#define NTHR (WPB * 64)        // 832 threads

typedef __attribute__((ext_vector_type(8))) __bf16 bf16x8;
typedef __attribute__((ext_vector_type(4))) float f32x4;

// ws layout (bytes):
//       0 : WmT bf16 [256][256]   (131072)
//  131072 : proj f32 [256]        (1024)
//  132096 : At   f32 [100000]     (400000)
//  532096 : part2 float2[256]     (2048)
//  536192 : s1g  f32[256]         (1024)
//  537216 : s0g  f32[256]         (1024)
//  538240 : lse  f32              (4)

__device__ __forceinline__ float tanh_fast(float x) {
    float e = __expf(2.0f * x);
    return 1.0f - 2.0f / (e + 1.0f);
}

// ---------------------------------------------------------------- prep
__global__ __launch_bounds__(256) void k_prep(const float* __restrict__ Wm,
                                              const float* __restrict__ hc,
                                              const float* __restrict__ W1,
                                              __bf16* __restrict__ WmT,
                                              float* __restrict__ proj,
                                              float* __restrict__ At,
                                              float* __restrict__ s1g,
                                              float* __restrict__ s0g) {
    const int j = blockIdx.x;
    const int t = threadIdx.x;
    WmT[j * H_N + t] = (__bf16)Wm[t * H_N + j];   // B^T, k-contiguous
    __shared__ float red[H_N];
    red[t] = hc[t] * W1[j * H_N + t];
    __syncthreads();
    for (int off = 128; off > 0; off >>= 1) {
        if (t < off) red[t] += red[t + off];
        __syncthreads();
    }
    if (t == 0) proj[j] = red[0];
    if (j == 0) { s1g[t] = 0.0f; s0g[t] = 0.0f; }
    // zero the At accumulator (atomicAdd target, re-zeroed every call)
    for (int i = j * 256 + t; i < T_N; i += 65536) At[i] = 0.0f;
}

// ---------------------------------------------------------------- fused At-partial + ct partials
// R15 structure with HALF-B blocks: block (pair,half) holds B cols
// [128*half, 128*half+128) in 64 KB LDS -> 2 blocks/CU -> 26 waves/CU
// (2x R15's TLP). Wave gw = pair*13+w owns one 32-row tile; computes the
// 128-col partial of At (global atomicAdd, 2 contributors, deterministic),
// and ct partials via the own-partial linearity identity (exact).
// Blocks b and b+256 (same XCD) share the tile's A rows in L2.
__global__ __launch_bounds__(NTHR, 4) void k_at(const float* __restrict__ Mt,
                                                const __bf16* __restrict__ WmT,
                                                const float* __restrict__ proj,
                                                const float* __restrict__ V,
                                                float* __restrict__ At,
                                                float* __restrict__ s1g,
                                                float* __restrict__ s0g) {
    const int tid = threadIdx.x;
    const int lane = tid & 63;
    const int w = tid >> 6;     // 0..12
    const int l15 = lane & 15;
    const int lg = lane >> 4;   // 0..3

    const int half = blockIdx.x >> 8;    // 0 or 1 (b and b+256 pair)
    const int pairb = blockIdx.x & 255;  // 0..255

    struct SMem {
        __align__(16) char sB[65536];    // [n_loc=128][k=256] bf16, XOR-swizzled
        float pj[128];
        float vj[128];
    };
    __shared__ SMem sm;

    // ---- B prologue: this block's 128-col half (WmT L2-hot after k_prep)
    for (int g = tid; g < 4096; g += NTHR) {
        const int nl = g >> 5;           // local col 0..127
        const int c = g & 31;
        const bf16x8 v = *(const bf16x8*)(WmT + (128 * half + nl) * H_N + c * 8);
        *(bf16x8*)(&sm.sB[(nl * 512 + c * 16) ^ ((nl & 7) << 4)]) = v;
    }
    if (tid < 128) {
        sm.pj[tid] = proj[128 * half + tid];
        sm.vj[tid] = V[128 * half + tid];
    }
    __syncthreads();

    const int gw = pairb * WPB + w;   // tile id
    float s1a[4] = {0.f, 0.f, 0.f, 0.f};
    float s0a[4] = {0.f, 0.f, 0.f, 0.f};

    if (gw < NT32) {
        const int t0 = gw * 32;
        const float* arow0 = Mt + (size_t)(t0 + l15) * H_N;
        const float* arow1 = Mt + (size_t)(t0 + 16 + l15) * H_N;

        // ---- A fragments for both row-groups (cvt at load)
        bf16x8 af0[8], af1[8];
#pragma unroll
        for (int ks = 0; ks < 8; ++ks) {
            const float4 a0 = *(const float4*)(arow0 + 32 * ks + 8 * lg);
            const float4 a1 = *(const float4*)(arow0 + 32 * ks + 8 * lg + 4);
            af0[ks][0] = (__bf16)a0.x; af0[ks][1] = (__bf16)a0.y;
            af0[ks][2] = (__bf16)a0.z; af0[ks][3] = (__bf16)a0.w;
            af0[ks][4] = (__bf16)a1.x; af0[ks][5] = (__bf16)a1.y;
            af0[ks][6] = (__bf16)a1.z; af0[ks][7] = (__bf16)a1.w;
            const float4 b0 = *(const float4*)(arow1 + 32 * ks + 8 * lg);
            const float4 b1 = *(const float4*)(arow1 + 32 * ks + 8 * lg + 4);
            af1[ks][0] = (__bf16)b0.x; af1[ks][1] = (__bf16)b0.y;
            af1[ks][2] = (__bf16)b0.z; af1[ks][3] = (__bf16)b0.w;
            af1[ks][4] = (__bf16)b1.x; af1[ks][5] = (__bf16)b1.y;
            af1[ks][6] = (__bf16)b1.z; af1[ks][7] = (__bf16)b1.w;
        }

        // ---- jb loop: 8 local col-blocks; B-reads shared by both row-groups
        float pacc0[4] = {0.f, 0.f, 0.f, 0.f};
        float pacc1[4] = {0.f, 0.f, 0.f, 0.f};
#pragma unroll 1
        for (int jb = 0; jb < 8; ++jb) {
            f32x4 a0A = {0.f, 0.f, 0.f, 0.f}, a0B = {0.f, 0.f, 0.f, 0.f};
            f32x4 a1A = {0.f, 0.f, 0.f, 0.f}, a1B = {0.f, 0.f, 0.f, 0.f};
            const int nl = 16 * jb + l15;      // local col
            const int nb = nl * 512;
            const int nswz = (nl & 7) << 4;
#pragma unroll
            for (int ks = 0; ks < 4; ++ks) {
                const bf16x8 bfA = *(const bf16x8*)(
                    &sm.sB[nb + (((32 * ks + 8 * lg) * 2) ^ nswz)]);
                const bf16x8 bfB = *(const bf16x8*)(
                    &sm.sB[nb + (((32 * (ks + 4) + 8 * lg) * 2) ^ nswz)]);
                a0A = __builtin_amdgcn_mfma_f32_16x16x32_bf16(af0[ks], bfA, a0A, 0, 0, 0);
                a1A = __builtin_amdgcn_mfma_f32_16x16x32_bf16(af1[ks], bfA, a1A, 0, 0, 0);
                a0B = __builtin_amdgcn_mfma_f32_16x16x32_bf16(af0[ks + 4], bfB, a0B, 0, 0, 0);
                a1B = __builtin_amdgcn_mfma_f32_16x16x32_bf16(af1[ks + 4], bfB, a1B, 0, 0, 0);
            }
            const float pjv = sm.pj[nl], vjv = sm.vj[nl];
#pragma unroll
            for (int i = 0; i < 4; ++i) {
                pacc0[i] += tanh_fast(a0A[i] + a0B[i] + pjv) * vjv;
                pacc1[i] += tanh_fast(a1A[i] + a1B[i] + pjv) * vjv;
            }
        }

        // ---- row sums (this half's 128-col partial): butterfly over 16 lanes
        float p0[4], p1[4];
#pragma unroll
        for (int i = 0; i < 4; ++i) {
            float q0 = pacc0[i], q1 = pacc1[i];
            q0 += __shfl_xor(q0, 1); q1 += __shfl_xor(q1, 1);
            q0 += __shfl_xor(q0, 2); q1 += __shfl_xor(q1, 2);
            q0 += __shfl_xor(q0, 4); q1 += __shfl_xor(q1, 4);
            q0 += __shfl_xor(q0, 8); q1 += __shfl_xor(q1, 8);
            p0[i] = q0; p1[i] = q1;
        }
        if (l15 == 0) {
#pragma unroll
            for (int i = 0; i < 4; ++i) {
                atomicAdd(&At[t0 + 4 * lg + i], p0[i]);
                atomicAdd(&At[t0 + 16 + 4 * lg + i], p1[i]);
            }
        }

        // ---- ct partials: own-half p x own rows (exact by linearity);
        //      fp32 re-read is L2-hot (rows just fetched for af)
        const float* crow = Mt + (size_t)t0 * H_N + lane * 4;
        {
            float4 x[16];
#pragma unroll
            for (int r = 0; r < 16; ++r)
                x[r] = *(const float4*)(crow + (size_t)r * H_N);
#pragma unroll
            for (int r = 0; r < 16; ++r) {
                const float atr = __shfl(p0[r & 3], 16 * (r >> 2));
                s1a[0] += atr * x[r].x; s1a[1] += atr * x[r].y;
                s1a[2] += atr * x[r].z; s1a[3] += atr * x[r].w;
                if (half == 0) {
                    s0a[0] += x[r].x; s0a[1] += x[r].y;
                    s0a[2] += x[r].z; s0a[3] += x[r].w;
                }
            }
#pragma unroll
            for (int r = 0; r < 16; ++r)
                x[r] = *(const float4*)(crow + (size_t)(16 + r) * H_N);
#pragma unroll
            for (int r = 0; r < 16; ++r) {
                const float atr = __shfl(p1[r & 3], 16 * (r >> 2));
                s1a[0] += atr * x[r].x; s1a[1] += atr * x[r].y;
                s1a[2] += atr * x[r].z; s1a[3] += atr * x[r].w;
                if (half == 0) {
                    s0a[0] += x[r].x; s0a[1] += x[r].y;
                    s0a[2] += x[r].z; s0a[3] += x[r].w;
                }
            }
        }
    }

    // ---- block reduce of ct partials (reuse sB region)
    __syncthreads();
    float* red1 = (float*)&sm.sB[0];       // [13][256]
    float* red2 = (float*)&sm.sB[16384];   // [13][256]
#pragma unroll
    for (int q = 0; q < 4; ++q) {
        red1[w * 256 + lane * 4 + q] = s1a[q];
        red2[w * 256 + lane * 4 + q] = s0a[q];
    }
    __syncthreads();
    if (tid < 256) {
        float a = 0.f;
#pragma unroll
        for (int g = 0; g < WPB; ++g) a += red1[g * 256 + tid];
        atomicAdd(&s1g[tid], a);
    } else if (tid < 512 && half == 0) {
        const int c = tid - 256;
        float a = 0.f;
#pragma unroll
        for (int g = 0; g < WPB; ++g) a += red2[g * 256 + c];
        atomicAdd(&s0g[c], a);
    }
}

// ---------------------------------------------------------------- LSE stage 1 (reads completed At)
__global__ __launch_bounds__(256) void k_lse_part(const float* __restrict__ At,
                                                  float2* __restrict__ part) {
    const int tid = threadIdx.x;
    const int gid = blockIdx.x * 256 + tid;
    float m = -1e30f, s = 0.0f;
    for (int i = gid; i < T_N; i += 256 * 256) {
        const float x = At[i];
        if (x > m) { s = s * __expf(m - x) + 1.0f; m = x; }
        else s += __expf(x - m);
    }
    __shared__ float ms[256], ss[256];
    ms[tid] = m; ss[tid] = s;
    __syncthreads();
    for (int off = 128; off > 0; off >>= 1) {
        if (tid < off) {
            const float m2 = ms[tid + off], s2 = ss[tid + off];
            const float M = fmaxf(ms[tid], m2);
            ss[tid] = ss[tid] * __expf(ms[tid] - M) + s2 * __expf(m2 - M);
            ms[tid] = M;
        }
        __syncthreads();
    }
    if (tid == 0) part[blockIdx.x] = make_float2(ms[0], ss[0]);
}

// ---------------------------------------------------------------- final: LSE + ct
__global__ __launch_bounds__(256) void k_final(const float2* __restrict__ part2,
                                               const float* __restrict__ s1g,
                                               const float* __restrict__ s0g,
                                               float* __restrict__ lse,
                                               float* __restrict__ out) {
    const int tid = threadIdx.x;
    __shared__ float ms[256], ss[256];
    const float2 p = part2[tid];
    ms[tid] = p.x; ss[tid] = p.y;
    __syncthreads();
    for (int off = 128; off > 0; off >>= 1) {
        if (tid < off) {
            const float m2 = ms[tid + off], s2 = ss[tid + off];
            const float M = fmaxf(ms[tid], m2);
            ss[tid] = ss[tid] * __expf(ms[tid] - M) + s2 * __expf(m2 - M);
            ms[tid] = M;
        }
        __syncthreads();
    }
    __shared__ float Ls;
    if (tid == 0) { Ls = ms[0] + logf(ss[0]); *lse = Ls; }
    __syncthreads();
    out[T_N + tid] = s1g[tid] - Ls * s0g[tid];
}

// ---------------------------------------------------------------- alphat = At - LSE
__global__ __launch_bounds__(256) void k_alpha(const float* __restrict__ At,
                                               const float* __restrict__ lse,
                                               float* __restrict__ out) {
    const float L = *lse;
    const int i4 = blockIdx.x * 256 + threadIdx.x;
    if (i4 < T_N / 4) {
        float4 a = *(const float4*)(At + i4 * 4);
        a.x -= L; a.y -= L; a.z -= L; a.w -= L;
        *(float4*)(out + i4 * 4) = a;
    }
}

// ----------------------------------------------------------------
extern "C" void kernel_launch(void* const* d_in, const int* in_sizes, int n_in,
                              void* d_out, int out_size, void* d_ws, size_t ws_size,
                              hipStream_t stream) {
    const float* inputs = (const float*)d_in[0];  // (T, H)
    const float* hc     = (const float*)d_in[1];  // (1, H)
    const float* Wm     = (const float*)d_in[2];  // (H, H)
    const float* V      = (const float*)d_in[3];  // (H, 1)
    const float* W1     = (const float*)d_in[4];  // (H, H)
    float* out = (float*)d_out;                   // [alphat (T) | ct (H)]

    char* ws = (char*)d_ws;
    __bf16* WmT  = (__bf16*)ws;
    float* proj  = (float*)(ws + 131072);
    float* At    = (float*)(ws + 132096);
    float2* p2   = (float2*)(ws + 532096);
    float* s1g   = (float*)(ws + 536192);
    float* s0g   = (float*)(ws + 537216);
    float* lse   = (float*)(ws + 538240);

    k_prep<<<256, 256, 0, stream>>>(Wm, hc, W1, WmT, proj, At, s1g, s0g);
    k_at<<<NB_AT, NTHR, 0, stream>>>(inputs, WmT, proj, V, At, s1g, s0g);
    k_lse_part<<<256, 256, 0, stream>>>(At, p2);
    k_final<<<1, 256, 0, stream>>>(p2, s1g, s0g, lse, out);
    k_alpha<<<98, 256, 0, stream>>>(At, lse, out);
}

// Round 22
// 55.595 us; speedup vs baseline: 2.4794x; 1.5521x over previous
//
#include <hip/hip_runtime.h>
#include <math.h>

#define T_N 100000
#define H_N 256
#define NT32 (T_N / 32)        // 3125 32-row tiles, exact
#define NB_AT 256              // k_at grid
#define WPB 13                 // waves per block
#define NTHR (WPB * 64)        // 832 threads

typedef __attribute__((ext_vector_type(8))) __bf16 bf16x8;
typedef __attribute__((ext_vector_type(4))) float f32x4;

// ws layout (bytes):
//       0 : WmT bf16 [256][256]   (131072)
//  131072 : proj f32 [256]        (1024)
//  132096 : At   f32 [100000]     (400000)
//  532096 : part2 float2[256]     (2048)
//  536192 : s1g  f32[256]         (1024)
//  537216 : s0g  f32[256]         (1024)
//  538240 : lse  f32              (4)

__device__ __forceinline__ float tanh_fast(float x) {
    float e = __expf(2.0f * x);
    return 1.0f - 2.0f / (e + 1.0f);
}

// ---------------------------------------------------------------- prep
__global__ __launch_bounds__(256) void k_prep(const float* __restrict__ Wm,
                                              const float* __restrict__ hc,
                                              const float* __restrict__ W1,
                                              __bf16* __restrict__ WmT,
                                              float* __restrict__ proj,
                                              float* __restrict__ s1g,
                                              float* __restrict__ s0g) {
    const int j = blockIdx.x;
    const int t = threadIdx.x;
    WmT[j * H_N + t] = (__bf16)Wm[t * H_N + j];   // B^T, k-contiguous
    __shared__ float red[H_N];
    red[t] = hc[t] * W1[j * H_N + t];
    __syncthreads();
    for (int off = 128; off > 0; off >>= 1) {
        if (t < off) red[t] += red[t + off];
        __syncthreads();
    }
    if (t == 0) proj[j] = red[0];
    if (j == 0) { s1g[t] = 0.0f; s0g[t] = 0.0f; }
}

// ---------------------------------------------------------------- fused At + LSE + ct partials
// R15 champion structure: 832 thr = 13 waves, ONE 32-row tile per wave, no
// main-loop barriers, B (256x256 bf16) in LDS. R22 deltas only:
//  (1) per-wave jb rotation (start col-block = 3w mod 16) so the 13 waves'
//      LDS/VALU/MFMA phases interleave instead of bursting in lockstep;
//  (2) s_setprio(1) around the jb loop (T5: waves in compute phase win
//      issue arbitration over waves waiting on loads).
__global__ __launch_bounds__(NTHR, 4) void k_at(const float* __restrict__ Mt,
                                                const __bf16* __restrict__ WmT,
                                                const float* __restrict__ proj,
                                                const float* __restrict__ V,
                                                float* __restrict__ At,
                                                float2* __restrict__ part2,
                                                float* __restrict__ s1g,
                                                float* __restrict__ s0g) {
    const int tid = threadIdx.x;
    const int lane = tid & 63;
    const int w = tid >> 6;     // 0..12
    const int l15 = lane & 15;
    const int lg = lane >> 4;   // 0..3

    struct SMem {
        __align__(16) char sB[131072];   // [n=256][k=256] bf16, XOR-swizzled
        float pj[256];
        float vj[256];
        float lsem[WPB], lses[WPB];
    };
    __shared__ SMem sm;

    // ---- B prologue (WmT L2-hot after k_prep)
    for (int g = tid; g < 8192; g += NTHR) {
        const int n = g >> 5;
        const int c = g & 31;
        const bf16x8 v = *(const bf16x8*)(WmT + n * H_N + c * 8);
        *(bf16x8*)(&sm.sB[(n * 512 + c * 16) ^ ((n & 7) << 4)]) = v;
    }
    if (tid < 256) { sm.pj[tid] = proj[tid]; sm.vj[tid] = V[tid]; }
    __syncthreads();

    const int gw = blockIdx.x * WPB + w;   // global wave id = tile id
    float lm = -1e30f, ls = 0.0f;
    float s1a[4] = {0.f, 0.f, 0.f, 0.f};
    float s0a[4] = {0.f, 0.f, 0.f, 0.f};

    if (gw < NT32) {
        const int t0 = gw * 32;
        const float* arow0 = Mt + (size_t)(t0 + l15) * H_N;
        const float* arow1 = Mt + (size_t)(t0 + 16 + l15) * H_N;

        // ---- A fragments for both row-groups (cvt at load; 64 VGPR total)
        bf16x8 af0[8], af1[8];
#pragma unroll
        for (int ks = 0; ks < 8; ++ks) {
            const float4 a0 = *(const float4*)(arow0 + 32 * ks + 8 * lg);
            const float4 a1 = *(const float4*)(arow0 + 32 * ks + 8 * lg + 4);
            af0[ks][0] = (__bf16)a0.x; af0[ks][1] = (__bf16)a0.y;
            af0[ks][2] = (__bf16)a0.z; af0[ks][3] = (__bf16)a0.w;
            af0[ks][4] = (__bf16)a1.x; af0[ks][5] = (__bf16)a1.y;
            af0[ks][6] = (__bf16)a1.z; af0[ks][7] = (__bf16)a1.w;
            const float4 b0 = *(const float4*)(arow1 + 32 * ks + 8 * lg);
            const float4 b1 = *(const float4*)(arow1 + 32 * ks + 8 * lg + 4);
            af1[ks][0] = (__bf16)b0.x; af1[ks][1] = (__bf16)b0.y;
            af1[ks][2] = (__bf16)b0.z; af1[ks][3] = (__bf16)b0.w;
            af1[ks][4] = (__bf16)b1.x; af1[ks][5] = (__bf16)b1.y;
            af1[ks][6] = (__bf16)b1.z; af1[ks][7] = (__bf16)b1.w;
        }

        // ---- jb loop: 16 col-blocks, per-wave rotated start; B-reads shared
        const int jboff = (3 * w) & 15;
        float pacc0[4] = {0.f, 0.f, 0.f, 0.f};
        float pacc1[4] = {0.f, 0.f, 0.f, 0.f};
        __builtin_amdgcn_s_setprio(1);
#pragma unroll 1
        for (int jbi = 0; jbi < 16; ++jbi) {
            const int jb = (jbi + jboff) & 15;
            f32x4 a0A = {0.f, 0.f, 0.f, 0.f}, a0B = {0.f, 0.f, 0.f, 0.f};
            f32x4 a1A = {0.f, 0.f, 0.f, 0.f}, a1B = {0.f, 0.f, 0.f, 0.f};
            const int n = 16 * jb + l15;
            const int nb = n * 512;
            const int nswz = (n & 7) << 4;
#pragma unroll
            for (int ks = 0; ks < 4; ++ks) {
                const bf16x8 bfA = *(const bf16x8*)(
                    &sm.sB[nb + (((32 * ks + 8 * lg) * 2) ^ nswz)]);
                const bf16x8 bfB = *(const bf16x8*)(
                    &sm.sB[nb + (((32 * (ks + 4) + 8 * lg) * 2) ^ nswz)]);
                a0A = __builtin_amdgcn_mfma_f32_16x16x32_bf16(af0[ks], bfA, a0A, 0, 0, 0);
                a1A = __builtin_amdgcn_mfma_f32_16x16x32_bf16(af1[ks], bfA, a1A, 0, 0, 0);
                a0B = __builtin_amdgcn_mfma_f32_16x16x32_bf16(af0[ks + 4], bfB, a0B, 0, 0, 0);
                a1B = __builtin_amdgcn_mfma_f32_16x16x32_bf16(af1[ks + 4], bfB, a1B, 0, 0, 0);
            }
            const float pjv = sm.pj[n], vjv = sm.vj[n];
#pragma unroll
            for (int i = 0; i < 4; ++i) {
                pacc0[i] += tanh_fast(a0A[i] + a0B[i] + pjv) * vjv;
                pacc1[i] += tanh_fast(a1A[i] + a1B[i] + pjv) * vjv;
            }
        }
        __builtin_amdgcn_s_setprio(0);

        // ---- row sums: butterfly over the 16 lanes of each lg group
        float p0[4], p1[4];
#pragma unroll
        for (int i = 0; i < 4; ++i) {
            float q0 = pacc0[i], q1 = pacc1[i];
            q0 += __shfl_xor(q0, 1); q1 += __shfl_xor(q1, 1);
            q0 += __shfl_xor(q0, 2); q1 += __shfl_xor(q1, 2);
            q0 += __shfl_xor(q0, 4); q1 += __shfl_xor(q1, 4);
            q0 += __shfl_xor(q0, 8); q1 += __shfl_xor(q1, 8);
            p0[i] = q0; p1[i] = q1;
        }
        if (l15 == 0) {
#pragma unroll
            for (int i = 0; i < 4; ++i) {
                const float a0v = p0[i], a1v = p1[i];
                At[t0 + 4 * lg + i] = a0v;
                At[t0 + 16 + 4 * lg + i] = a1v;
                if (a0v > lm) { ls = ls * __expf(lm - a0v) + 1.0f; lm = a0v; }
                else ls += __expf(a0v - lm);
                if (a1v > lm) { ls = ls * __expf(lm - a1v) + 1.0f; lm = a1v; }
                else ls += __expf(a1v - lm);
            }
        }

        // ---- ct partials: re-read fp32 tile (L2-hot; af[] regs now free)
        const float* crow = Mt + (size_t)t0 * H_N + lane * 4;
        {
            float4 x[16];
#pragma unroll
            for (int r = 0; r < 16; ++r)
                x[r] = *(const float4*)(crow + (size_t)r * H_N);
#pragma unroll
            for (int r = 0; r < 16; ++r) {
                const float atr = __shfl(p0[r & 3], 16 * (r >> 2));
                s1a[0] += atr * x[r].x; s1a[1] += atr * x[r].y;
                s1a[2] += atr * x[r].z; s1a[3] += atr * x[r].w;
                s0a[0] += x[r].x; s0a[1] += x[r].y;
                s0a[2] += x[r].z; s0a[3] += x[r].w;
            }
#pragma unroll
            for (int r = 0; r < 16; ++r)
                x[r] = *(const float4*)(crow + (size_t)(16 + r) * H_N);
#pragma unroll
            for (int r = 0; r < 16; ++r) {
                const float atr = __shfl(p1[r & 3], 16 * (r >> 2));
                s1a[0] += atr * x[r].x; s1a[1] += atr * x[r].y;
                s1a[2] += atr * x[r].z; s1a[3] += atr * x[r].w;
                s0a[0] += x[r].x; s0a[1] += x[r].y;
                s0a[2] += x[r].z; s0a[3] += x[r].w;
            }
        }
    }

    // ---- wave LSE partial -> shared
#pragma unroll
    for (int d = 1; d < 64; d <<= 1) {
        const float m2 = __shfl_xor(lm, d), s2 = __shfl_xor(ls, d);
        const float M = fmaxf(lm, m2);
        ls = ls * __expf(lm - M) + s2 * __expf(m2 - M);
        lm = M;
    }
    if (lane == 0) { sm.lsem[w] = lm; sm.lses[w] = ls; }

    // ---- block reduce of ct partials (reuse sB region)
    __syncthreads();
    float* red1 = (float*)&sm.sB[0];       // [13][256]
    float* red2 = (float*)&sm.sB[65536];   // [13][256]
#pragma unroll
    for (int q = 0; q < 4; ++q) {
        red1[w * 256 + lane * 4 + q] = s1a[q];
        red2[w * 256 + lane * 4 + q] = s0a[q];
    }
    __syncthreads();
    if (tid < 256) {
        float a = 0.f;
#pragma unroll
        for (int g = 0; g < WPB; ++g) a += red1[g * 256 + tid];
        atomicAdd(&s1g[tid], a);
    } else if (tid < 512) {
        const int c = tid - 256;
        float a = 0.f;
#pragma unroll
        for (int g = 0; g < WPB; ++g) a += red2[g * 256 + c];
        atomicAdd(&s0g[c], a);
    } else if (tid == 512) {
        float m = sm.lsem[0], s = sm.lses[0];
#pragma unroll
        for (int g = 1; g < WPB; ++g) {
            const float m2 = sm.lsem[g], s2 = sm.lses[g];
            const float M = fmaxf(m, m2);
            s = s * __expf(m - M) + s2 * __expf(m2 - M);
            m = M;
        }
        part2[blockIdx.x] = make_float2(m, s);
    }
}

// ---------------------------------------------------------------- final: LSE + ct
__global__ __launch_bounds__(256) void k_final(const float2* __restrict__ part2,
                                               const float* __restrict__ s1g,
                                               const float* __restrict__ s0g,
                                               float* __restrict__ lse,
                                               float* __restrict__ out) {
    const int tid = threadIdx.x;
    __shared__ float ms[256], ss[256];
    const float2 p = part2[tid];
    ms[tid] = p.x; ss[tid] = p.y;
    __syncthreads();
    for (int off = 128; off > 0; off >>= 1) {
        if (tid < off) {
            const float m2 = ms[tid + off], s2 = ss[tid + off];
            const float M = fmaxf(ms[tid], m2);
            ss[tid] = ss[tid] * __expf(ms[tid] - M) + s2 * __expf(m2 - M);
            ms[tid] = M;
        }
        __syncthreads();
    }
    __shared__ float Ls;
    if (tid == 0) { Ls = ms[0] + logf(ss[0]); *lse = Ls; }
    __syncthreads();
    out[T_N + tid] = s1g[tid] - Ls * s0g[tid];
}

// ---------------------------------------------------------------- alphat = At - LSE
__global__ __launch_bounds__(256) void k_alpha(const float* __restrict__ At,
                                               const float* __restrict__ lse,
                                               float* __restrict__ out) {
    const float L = *lse;
    const int i4 = blockIdx.x * 256 + threadIdx.x;
    if (i4 < T_N / 4) {
        float4 a = *(const float4*)(At + i4 * 4);
        a.x -= L; a.y -= L; a.z -= L; a.w -= L;
        *(float4*)(out + i4 * 4) = a;
    }
}

// ----------------------------------------------------------------
extern "C" void kernel_launch(void* const* d_in, const int* in_sizes, int n_in,
                              void* d_out, int out_size, void* d_ws, size_t ws_size,
                              hipStream_t stream) {
    const float* inputs = (const float*)d_in[0];  // (T, H)
    const float* hc     = (const float*)d_in[1];  // (1, H)
    const float* Wm     = (const float*)d_in[2];  // (H, H)
    const float* V      = (const float*)d_in[3];  // (H, 1)
    const float* W1     = (const float*)d_in[4];  // (H, H)
    float* out = (float*)d_out;                   // [alphat (T) | ct (H)]

    char* ws = (char*)d_ws;
    __bf16* WmT  = (__bf16*)ws;
    float* proj  = (float*)(ws + 131072);
    float* At    = (float*)(ws + 132096);
    float2* p2   = (float2*)(ws + 532096);
    float* s1g   = (float*)(ws + 536192);
    float* s0g   = (float*)(ws + 537216);
    float* lse   = (float*)(ws + 538240);

    k_prep<<<256, 256, 0, stream>>>(Wm, hc, W1, WmT, proj, s1g, s0g);
    k_at<<<NB_AT, NTHR, 0, stream>>>(inputs, WmT, proj, V, At, p2, s1g, s0g);
    k_final<<<1, 256, 0, stream>>>(p2, s1g, s0g, lse, out);
    k_alpha<<<98, 256, 0, stream>>>(At, lse, out);
}